// Round 4
// baseline (509.760 us; speedup 1.0000x reference)
//
#include <hip/hip_runtime.h>
#include <hip/hip_bf16.h>

#define BB 8192
#define SS 20
#define DD 300
#define JJ 512
#define NII 1000
#define VGG 2078
#define KP 320          // k2 K padded (10 k-steps of 32)
#define RB 640          // k2 A LDS row bytes = KP*2 (40 16B-blocks, mult of 8)
#define BRB 384         // k2 B half-tile LDS row bytes (24 16B-blocks, mult of 8)
#define BP1 72          // k1 64x64 chunk lds row stride

typedef __attribute__((ext_vector_type(8))) short short8v;
typedef __attribute__((ext_vector_type(4))) float float4v;

// tanh(x) = 1 - 2/(exp(2x)+1) ; exp2-based, 5 instrs, saturates correctly
__device__ __forceinline__ float tanh_fast(float x) {
    float t = __expf(2.f * x);
    return 1.f - 2.f * __builtin_amdgcn_rcpf(t + 1.f);
}

__device__ __forceinline__ unsigned short bf16u(float x) {
    __hip_bfloat16 h = __float2bfloat16(x);
    return *(unsigned short*)&h;
}

// ---------------- pad+convert fp32 -> bf16 with zero pad on cols ----------------
__global__ __launch_bounds__(256) void kc_pad_bf16(const float* __restrict__ src,
                                                   __hip_bfloat16* __restrict__ dst,
                                                   int rows, int scols, int dcols) {
    int idx = blockIdx.x * 256 + threadIdx.x;
    if (idx >= rows * dcols) return;
    int r = idx / dcols, c = idx % dcols;
    float v = (c < scols) ? src[(long)r * scols + c] : 0.f;
    dst[idx] = __float2bfloat16(v);
}

// ---------------- kernel 0: valid / nonzero masks ----------------
__global__ __launch_bounds__(256) void k0_valid(const int* __restrict__ labels,
                                                float* __restrict__ valid,
                                                float* __restrict__ nonzero) {
    int b = blockIdx.x * blockDim.x + threadIdx.x;
    if (b >= BB) return;
    float v = 1.f;
    for (int s = 0; s < SS; ++s) {
        float nz = (labels[b * SS + s] != 0) ? 1.f : 0.f;
        v *= nz;
        nonzero[b * SS + s] = nz;
        valid[b * SS + s] = v;
    }
}

// ---------------- kernel 1 (MFMA): femb = bf16(guide @ W_emb^T + b_emb) --------
__global__ __launch_bounds__(256) void k1_femb_mfma(
    const __hip_bfloat16* __restrict__ Gb,   // [NII][2112]
    const __hip_bfloat16* __restrict__ Web,  // [JJ][2112]
    const float* __restrict__ b_emb,
    __hip_bfloat16* __restrict__ femb) {     // [1024][JJ]
    __shared__ __hip_bfloat16 Al[64 * BP1];
    __shared__ __hip_bfloat16 Bl[64 * BP1];
    const int t = threadIdx.x;
    const int m0 = blockIdx.x * 64;
    const int n0 = blockIdx.y * 64;
    const int lane = t & 63;
    const int w = t >> 6;
    const int wm = w >> 1, wn = w & 1;
    const int li = lane & 15, lq = lane >> 4;

    float4v acc[2][2] = {};

    for (int kt = 0; kt < 33; ++kt) {
        for (int c = t; c < 512; c += 256) {
            int rr = c >> 3, off = (c & 7) * 8;
            int gr = m0 + rr; if (gr > NII - 1) gr = NII - 1;
            *(uint4*)&Al[rr * BP1 + off] =
                *(const uint4*)(Gb + (long)gr * 2112 + kt * 64 + off);
            *(uint4*)&Bl[rr * BP1 + off] =
                *(const uint4*)(Web + (long)(n0 + rr) * 2112 + kt * 64 + off);
        }
        __syncthreads();
#pragma unroll
        for (int ks = 0; ks < 2; ++ks) {
            short8v a[2], b[2];
#pragma unroll
            for (int mt = 0; mt < 2; ++mt)
                a[mt] = *(const short8v*)&Al[(wm * 32 + mt * 16 + li) * BP1 + ks * 32 + lq * 8];
#pragma unroll
            for (int nt = 0; nt < 2; ++nt)
                b[nt] = *(const short8v*)&Bl[(wn * 32 + nt * 16 + li) * BP1 + ks * 32 + lq * 8];
#pragma unroll
            for (int mt = 0; mt < 2; ++mt)
#pragma unroll
                for (int nt = 0; nt < 2; ++nt)
                    acc[mt][nt] = __builtin_amdgcn_mfma_f32_16x16x32_bf16(
                        a[mt], b[nt], acc[mt][nt], 0, 0, 0);
        }
        __syncthreads();
    }
#pragma unroll
    for (int nt = 0; nt < 2; ++nt) {
        int col = n0 + wn * 32 + nt * 16 + li;
        float be = b_emb[col];
#pragma unroll
        for (int mt = 0; mt < 2; ++mt)
#pragma unroll
            for (int reg = 0; reg < 4; ++reg) {
                int row = wm * 32 + mt * 16 + lq * 4 + reg;
                femb[(long)(m0 + row) * JJ + col] = __float2bfloat16(acc[mt][nt][reg] + be);
            }
    }
}

// ---------------- kernel 2 (MFMA): fused scores -------------------------------
// M=B*S=163840, N=512 (8 jt), K=320 split in 2 halves of 160.
// LDS: A-stage [0,40960) unioned with Bbuf0 [0,24576)+Bbuf1 [24576,49152);
// femb rows [49152,54272). Total 54272 B -> 3 blocks/CU.
__global__ __launch_bounds__(256, 3) void k2_scores_mfma(
    const float* __restrict__ context,
    const __hip_bfloat16* __restrict__ Wsb,  // [JJ][KP]
    const float* __restrict__ b_sent,
    const float* __restrict__ w_fc,
    const float* __restrict__ b_fc,
    const __hip_bfloat16* __restrict__ femb, // [1024][JJ]
    const int* __restrict__ ann,
    const float* __restrict__ b_emb,
    const float* __restrict__ valid,
    float* __restrict__ scores) {
    __shared__ __align__(16) char smem[54272];
    char* abuf   = smem;                 // A-stage, 64*RB = 40960
    char* bbuf0  = smem;                 // B half kh=0, 64*BRB = 24576
    char* bbuf1  = smem + 24576;         // B half kh=1
    char* femb_l = smem + 49152;         // 5 rows * 512 * 2B = 5120

    const int t = threadIdx.x;
    const int m0 = blockIdx.x * 64;
    const int b_lo = m0 / SS;
    const int lane = t & 63;
    const int w = t >> 6;
    const int wm = w >> 1, wn = w & 1;
    const int li = lane & 15, lq = lane >> 4;

    // ---- stage A (context f32 -> bf16, XOR-swizzled) into abuf ----
    for (int idx = t; idx < 64 * 80; idx += 256) {
        int r = idx / 80, q = idx - (idx / 80) * 80;
        ushort4 pk;
        if (q < 75) {
            float4 v = *(const float4*)(context + (long)(m0 + r) * DD + q * 4);
            pk.x = bf16u(v.x); pk.y = bf16u(v.y); pk.z = bf16u(v.z); pk.w = bf16u(v.w);
        } else { pk.x = pk.y = pk.z = pk.w = 0; }
        int blk = (q >> 1) ^ (r & 7);
        *(ushort4*)(abuf + r * RB + (blk << 4) + ((q & 1) << 3)) = pk;
    }
    // ---- stage femb rows (<=5 distinct b) into femb_l ----
    for (int c = t; c < 320; c += 256) {
        int i = c >> 6, ch = c & 63;
        int b = b_lo + i; if (b > BB - 1) b = BB - 1;
        int grow = ann[2 * b];
        *(uint4*)(femb_l + i * 1024 + ch * 16) =
            *(const uint4*)(femb + (long)grow * JJ + ch * 8);
    }
    // ---- per-row-slot metadata ----
    int bbrel[8]; float vv[8];
#pragma unroll
    for (int mt = 0; mt < 2; ++mt)
#pragma unroll
        for (int reg = 0; reg < 4; ++reg) {
            int m = m0 + wm * 32 + mt * 16 + lq * 4 + reg;
            bbrel[mt * 4 + reg] = m / SS - b_lo;
            vv[mt * 4 + reg] = valid[m];
        }
    __syncthreads();

    // ---- A fragments -> registers (80 VGPR) ----
    short8v areg[2][10];
#pragma unroll
    for (int mt = 0; mt < 2; ++mt) {
        int r = wm * 32 + mt * 16 + li;
#pragma unroll
        for (int kt = 0; kt < 10; ++kt) {
            int blk = (kt * 4 + lq) ^ (r & 7);
            areg[mt][kt] = *(const short8v*)(abuf + r * RB + (blk << 4));
        }
    }
    // prefetch B(jt=0, kh=0) into regs while areg reads drain
    uint4 st[5];
#pragma unroll
    for (int i = 0; i < 5; ++i) {
        int c = i * 256 + t; int r = c / 20, c20 = c - r * 20;
        st[i] = *(const uint4*)(Wsb + (long)r * KP + c20 * 8);
    }
    __syncthreads();   // areg reads done; A region reusable
#pragma unroll
    for (int i = 0; i < 5; ++i) {
        int c = i * 256 + t; int r = c / 20, c20 = c - r * 20;
        *(uint4*)(bbuf0 + r * BRB + ((c20 ^ (r & 7)) << 4)) = st[i];
    }
    float sp[8] = {0.f, 0.f, 0.f, 0.f, 0.f, 0.f, 0.f, 0.f};
    __syncthreads();   // bbuf0 visible

    const int rb0 = wn * 32 + li;       // B frag row (nt=0); nt=1 adds 16
    const int xs0 = rb0 & 7, xs1 = (rb0 + 16) & 7;

    for (int jt = 0; jt < 8; ++jt) {
        float4v acc[2][2] = {};

        // ======== half kh=0: compute from bbuf0, prefetch (jt,kh=1)->bbuf1 ====
#pragma unroll
        for (int i = 0; i < 5; ++i) {
            int c = i * 256 + t; int r = c / 20, c20 = c - r * 20;
            st[i] = *(const uint4*)(Wsb + (long)(jt * 64 + r) * KP + 160 + c20 * 8);
        }
#pragma unroll
        for (int kt = 0; kt < 5; ++kt) {
            short8v b0 = *(const short8v*)(bbuf0 + rb0 * BRB + (((kt * 4 + lq) ^ xs0) << 4));
            short8v b1 = *(const short8v*)(bbuf0 + (rb0 + 16) * BRB + (((kt * 4 + lq) ^ xs1) << 4));
            acc[0][0] = __builtin_amdgcn_mfma_f32_16x16x32_bf16(areg[0][kt], b0, acc[0][0], 0, 0, 0);
            acc[0][1] = __builtin_amdgcn_mfma_f32_16x16x32_bf16(areg[0][kt], b1, acc[0][1], 0, 0, 0);
            acc[1][0] = __builtin_amdgcn_mfma_f32_16x16x32_bf16(areg[1][kt], b0, acc[1][0], 0, 0, 0);
            acc[1][1] = __builtin_amdgcn_mfma_f32_16x16x32_bf16(areg[1][kt], b1, acc[1][1], 0, 0, 0);
        }
#pragma unroll
        for (int i = 0; i < 5; ++i) {
            int c = i * 256 + t; int r = c / 20, c20 = c - r * 20;
            *(uint4*)(bbuf1 + r * BRB + ((c20 ^ (r & 7)) << 4)) = st[i];
        }
        __syncthreads();

        // ======== half kh=1: compute from bbuf1, prefetch (jt+1,kh=0)->bbuf0 ==
        if (jt < 7) {
#pragma unroll
            for (int i = 0; i < 5; ++i) {
                int c = i * 256 + t; int r = c / 20, c20 = c - r * 20;
                st[i] = *(const uint4*)(Wsb + (long)((jt + 1) * 64 + r) * KP + c20 * 8);
            }
        }
#pragma unroll
        for (int kt = 0; kt < 5; ++kt) {
            short8v b0 = *(const short8v*)(bbuf1 + rb0 * BRB + (((kt * 4 + lq) ^ xs0) << 4));
            short8v b1 = *(const short8v*)(bbuf1 + (rb0 + 16) * BRB + (((kt * 4 + lq) ^ xs1) << 4));
            acc[0][0] = __builtin_amdgcn_mfma_f32_16x16x32_bf16(areg[0][5 + kt], b0, acc[0][0], 0, 0, 0);
            acc[0][1] = __builtin_amdgcn_mfma_f32_16x16x32_bf16(areg[0][5 + kt], b1, acc[0][1], 0, 0, 0);
            acc[1][0] = __builtin_amdgcn_mfma_f32_16x16x32_bf16(areg[1][5 + kt], b0, acc[1][0], 0, 0, 0);
            acc[1][1] = __builtin_amdgcn_mfma_f32_16x16x32_bf16(areg[1][5 + kt], b1, acc[1][1], 0, 0, 0);
        }

        // fused epilogue: tanh + w_fc partial reduction (femb from LDS)
#pragma unroll
        for (int nt = 0; nt < 2; ++nt) {
            int col = jt * 64 + wn * 32 + nt * 16 + li;
            float bs = b_sent[col], wf = w_fc[col], be = b_emb[col];
#pragma unroll
            for (int mt = 0; mt < 2; ++mt)
#pragma unroll
                for (int reg = 0; reg < 4; ++reg) {
                    int slot = mt * 4 + reg;
                    float fv = __bfloat162float(
                        *(const __hip_bfloat16*)(femb_l + bbrel[slot] * 1024 + col * 2));
                    float guid = (vv[slot] != 0.f) ? fv : be;
                    sp[slot] += tanh_fast(acc[mt][nt][reg] + bs + guid) * wf;
                }
        }

        if (jt < 7) {
#pragma unroll
            for (int i = 0; i < 5; ++i) {
                int c = i * 256 + t; int r = c / 20, c20 = c - r * 20;
                *(uint4*)(bbuf0 + r * BRB + ((c20 ^ (r & 7)) << 4)) = st[i];
            }
        }
        __syncthreads();
    }

    // reduce across the 16 li lanes per row-slot
#pragma unroll
    for (int slot = 0; slot < 8; ++slot) {
        float v = sp[slot];
        v += __shfl_xor(v, 1); v += __shfl_xor(v, 2);
        v += __shfl_xor(v, 4); v += __shfl_xor(v, 8);
        sp[slot] = v;
    }
    float* red = (float*)smem;
    if (li == 0) {
#pragma unroll
        for (int mt = 0; mt < 2; ++mt)
#pragma unroll
            for (int reg = 0; reg < 4; ++reg)
                red[wn * 64 + wm * 32 + mt * 16 + lq * 4 + reg] = sp[mt * 4 + reg];
    }
    __syncthreads();
    if (t < 64) scores[m0 + t] = red[t] + red[64 + t] + b_fc[0];
}

// ---------------- kernel 3: softmax + mask + renorm + weighted sum -------------
__global__ __launch_bounds__(256) void k3_out(const float* __restrict__ scores,
                                              const float* __restrict__ nonzero,
                                              const float* __restrict__ embedded,
                                              float* __restrict__ out) {
    __shared__ float wgt[3][SS];
    const int b0 = blockIdx.x * 3;
    const int t = threadIdx.x;
    if (t < 3) {
        int b = b0 + t;
        if (b < BB) {
            float sc[SS], nz[SS];
            float mx = -1e30f;
            for (int s = 0; s < SS; ++s) {
                sc[s] = scores[b * SS + s];
                nz[s] = nonzero[b * SS + s];
                mx = fmaxf(mx, sc[s]);
            }
            float den = 0.f, e[SS];
            for (int s = 0; s < SS; ++s) { e[s] = nz[s] * __expf(sc[s] - mx); den += e[s]; }
            float inv = 1.f / den;
            for (int s = 0; s < SS; ++s) wgt[t][s] = e[s] * inv;
        }
    }
    __syncthreads();
    if (t < 225) {
        int r = t / 75, q = t - r * 75;
        int b = b0 + r;
        if (b < BB) {
            float4 a; a.x = a.y = a.z = a.w = 0.f;
#pragma unroll
            for (int s = 0; s < SS; ++s) {
                float4 e = *(const float4*)(embedded + ((long)b * SS + s) * DD + q * 4);
                float ww = wgt[r][s];
                a.x += ww * e.x; a.y += ww * e.y; a.z += ww * e.z; a.w += ww * e.w;
            }
            *(float4*)(out + (long)b * DD + q * 4) = a;
        }
    }
}

extern "C" void kernel_launch(void* const* d_in, const int* in_sizes, int n_in,
                              void* d_out, int out_size, void* d_ws, size_t ws_size,
                              hipStream_t stream) {
    const float* context  = (const float*)d_in[0];
    const float* embedded = (const float*)d_in[1];
    const int*   labels   = (const int*)d_in[2];
    const float* guide    = (const float*)d_in[3];
    const int*   ann      = (const int*)d_in[4];
    const float* W_sent   = (const float*)d_in[5];
    const float* b_sent   = (const float*)d_in[6];
    const float* W_emb    = (const float*)d_in[7];
    const float* b_emb    = (const float*)d_in[8];
    const float* w_fc     = (const float*)d_in[9];
    const float* b_fc     = (const float*)d_in[10];
    float* out = (float*)d_out;

    char* w = (char*)d_ws;
    __hip_bfloat16* femb = (__hip_bfloat16*)(w);               // 1024*512*2 = 1048576
    float* valid         = (float*)(w + 1048576);
    float* nonzero       = (float*)(w + 1703936);
    float* scores        = (float*)(w + 2359296);
    __hip_bfloat16* Wsb  = (__hip_bfloat16*)(w + 3014656);
    __hip_bfloat16* Web  = (__hip_bfloat16*)(w + 3342336);
    __hip_bfloat16* Gb   = (__hip_bfloat16*)(w + 5505024);
    // total 9729024 bytes

    hipLaunchKernelGGL(kc_pad_bf16, dim3((JJ * KP + 255) / 256), dim3(256), 0, stream,
                       W_sent, Wsb, JJ, DD, KP);
    hipLaunchKernelGGL(kc_pad_bf16, dim3((JJ * 2112 + 255) / 256), dim3(256), 0, stream,
                       W_emb, Web, JJ, VGG, 2112);
    hipLaunchKernelGGL(kc_pad_bf16, dim3((NII * 2112 + 255) / 256), dim3(256), 0, stream,
                       guide, Gb, NII, VGG, 2112);
    hipLaunchKernelGGL(k0_valid, dim3(BB / 256), dim3(256), 0, stream,
                       labels, valid, nonzero);
    hipLaunchKernelGGL(k1_femb_mfma, dim3(16, JJ / 64), dim3(256), 0, stream,
                       Gb, Web, b_emb, femb);
    hipLaunchKernelGGL(k2_scores_mfma, dim3((BB * SS) / 64), dim3(256), 0, stream,
                       context, Wsb, b_sent, w_fc, b_fc, femb, ann, b_emb, valid, scores);
    hipLaunchKernelGGL(k3_out, dim3((BB + 2) / 3), dim3(256), 0, stream,
                       scores, nonzero, embedded, out);
}

// Round 5
// 349.132 us; speedup vs baseline: 1.4601x; 1.4601x over previous
//
#include <hip/hip_runtime.h>
#include <hip/hip_bf16.h>

#define BB 8192
#define SS 20
#define DD 300
#define JJ 512
#define NII 1000
#define VGG 2078
#define KP 320          // k2 K padded (10 k-steps of 32)
#define RB 640          // k2 A LDS row bytes = KP*2 (40 16B-blocks, mult of 8)
#define BRB 384         // k2 B half-tile LDS row bytes (24 16B-blocks, mult of 8)
#define BP1 72          // k1 64x64 chunk lds row stride

typedef __attribute__((ext_vector_type(8))) short short8v;
typedef __attribute__((ext_vector_type(4))) float float4v;

// tanh(x) = 1 - 2/(exp(2x)+1) ; saturates correctly at +/-inf, no clamp needed
__device__ __forceinline__ float tanh_fast(float x) {
    float t = __expf(2.f * x);
    return 1.f - 2.f * __builtin_amdgcn_rcpf(t + 1.f);
}

__device__ __forceinline__ unsigned short bf16u(float x) {
    __hip_bfloat16 h = __float2bfloat16(x);
    return *(unsigned short*)&h;
}

// ---------------- pad+convert fp32 -> bf16 with zero pad on cols ----------------
__global__ __launch_bounds__(256) void kc_pad_bf16(const float* __restrict__ src,
                                                   __hip_bfloat16* __restrict__ dst,
                                                   int rows, int scols, int dcols) {
    int idx = blockIdx.x * 256 + threadIdx.x;
    if (idx >= rows * dcols) return;
    int r = idx / dcols, c = idx % dcols;
    float v = (c < scols) ? src[(long)r * scols + c] : 0.f;
    dst[idx] = __float2bfloat16(v);
}

// ---------------- kernel 0: valid / nonzero masks ----------------
__global__ __launch_bounds__(256) void k0_valid(const int* __restrict__ labels,
                                                float* __restrict__ valid,
                                                float* __restrict__ nonzero) {
    int b = blockIdx.x * blockDim.x + threadIdx.x;
    if (b >= BB) return;
    float v = 1.f;
    for (int s = 0; s < SS; ++s) {
        float nz = (labels[b * SS + s] != 0) ? 1.f : 0.f;
        v *= nz;
        nonzero[b * SS + s] = nz;
        valid[b * SS + s] = v;
    }
}

// ---------------- kernel 1 (MFMA): femb = bf16(guide @ W_emb^T + b_emb) --------
__global__ __launch_bounds__(256) void k1_femb_mfma(
    const __hip_bfloat16* __restrict__ Gb,   // [NII][2112]
    const __hip_bfloat16* __restrict__ Web,  // [JJ][2112]
    const float* __restrict__ b_emb,
    __hip_bfloat16* __restrict__ femb) {     // [1024][JJ]
    __shared__ __hip_bfloat16 Al[64 * BP1];
    __shared__ __hip_bfloat16 Bl[64 * BP1];
    const int t = threadIdx.x;
    const int m0 = blockIdx.x * 64;
    const int n0 = blockIdx.y * 64;
    const int lane = t & 63;
    const int w = t >> 6;
    const int wm = w >> 1, wn = w & 1;
    const int li = lane & 15, lq = lane >> 4;

    float4v acc[2][2] = {};

    for (int kt = 0; kt < 33; ++kt) {
        for (int c = t; c < 512; c += 256) {
            int rr = c >> 3, off = (c & 7) * 8;
            int gr = m0 + rr; if (gr > NII - 1) gr = NII - 1;
            *(uint4*)&Al[rr * BP1 + off] =
                *(const uint4*)(Gb + (long)gr * 2112 + kt * 64 + off);
            *(uint4*)&Bl[rr * BP1 + off] =
                *(const uint4*)(Web + (long)(n0 + rr) * 2112 + kt * 64 + off);
        }
        __syncthreads();
#pragma unroll
        for (int ks = 0; ks < 2; ++ks) {
            short8v a[2], b[2];
#pragma unroll
            for (int mt = 0; mt < 2; ++mt)
                a[mt] = *(const short8v*)&Al[(wm * 32 + mt * 16 + li) * BP1 + ks * 32 + lq * 8];
#pragma unroll
            for (int nt = 0; nt < 2; ++nt)
                b[nt] = *(const short8v*)&Bl[(wn * 32 + nt * 16 + li) * BP1 + ks * 32 + lq * 8];
#pragma unroll
            for (int mt = 0; mt < 2; ++mt)
#pragma unroll
                for (int nt = 0; nt < 2; ++nt)
                    acc[mt][nt] = __builtin_amdgcn_mfma_f32_16x16x32_bf16(
                        a[mt], b[nt], acc[mt][nt], 0, 0, 0);
        }
        __syncthreads();
    }
#pragma unroll
    for (int nt = 0; nt < 2; ++nt) {
        int col = n0 + wn * 32 + nt * 16 + li;
        float be = b_emb[col];
#pragma unroll
        for (int mt = 0; mt < 2; ++mt)
#pragma unroll
            for (int reg = 0; reg < 4; ++reg) {
                int row = wm * 32 + mt * 16 + lq * 4 + reg;
                femb[(long)(m0 + row) * JJ + col] = __float2bfloat16(acc[mt][nt][reg] + be);
            }
    }
}

// ---------------- kernel 2 (MFMA): fused scores -------------------------------
// M=B*S=163840, N=512 (8 jt), K=320 split in 2 halves of 160.
// LDS: A-stage [0,40960) unioned with Bbuf0 [0,24576)+Bbuf1 [24576,49152);
// femb rows [49152,54272). Total 54272 B -> LDS allows 3 blocks/CU.
// __launch_bounds__(256,2): VGPR cap 128 — the kernel's ~125-reg live set
// (areg 80 + st 20 + addressing; acc in AGPRs) fits WITHOUT spilling.
// (256,3) forced 84 VGPR -> 788 MB scratch traffic (round-4 regression).
__global__ __launch_bounds__(256, 2) void k2_scores_mfma(
    const float* __restrict__ context,
    const __hip_bfloat16* __restrict__ Wsb,  // [JJ][KP]
    const float* __restrict__ b_sent,
    const float* __restrict__ w_fc,
    const float* __restrict__ b_fc,
    const __hip_bfloat16* __restrict__ femb, // [1024][JJ]
    const int* __restrict__ ann,
    const float* __restrict__ b_emb,
    const float* __restrict__ valid,
    float* __restrict__ scores) {
    __shared__ __align__(16) char smem[54272];
    char* abuf   = smem;                 // A-stage, 64*RB = 40960
    char* bbuf0  = smem;                 // B half kh=0, 64*BRB = 24576
    char* bbuf1  = smem + 24576;         // B half kh=1
    char* femb_l = smem + 49152;         // 5 rows * 512 * 2B = 5120

    const int t = threadIdx.x;
    const int m0 = blockIdx.x * 64;
    const int b_lo = m0 / SS;
    const int lane = t & 63;
    const int w = t >> 6;
    const int wm = w >> 1, wn = w & 1;
    const int li = lane & 15, lq = lane >> 4;

    // ---- stage A (context f32 -> bf16, XOR-swizzled) into abuf ----
    for (int idx = t; idx < 64 * 80; idx += 256) {
        int r = idx / 80, q = idx - (idx / 80) * 80;
        ushort4 pk;
        if (q < 75) {
            float4 v = *(const float4*)(context + (long)(m0 + r) * DD + q * 4);
            pk.x = bf16u(v.x); pk.y = bf16u(v.y); pk.z = bf16u(v.z); pk.w = bf16u(v.w);
        } else { pk.x = pk.y = pk.z = pk.w = 0; }
        int blk = (q >> 1) ^ (r & 7);
        *(ushort4*)(abuf + r * RB + (blk << 4) + ((q & 1) << 3)) = pk;
    }
    // ---- stage femb rows (<=5 distinct b) into femb_l ----
    for (int c = t; c < 320; c += 256) {
        int i = c >> 6, ch = c & 63;
        int b = b_lo + i; if (b > BB - 1) b = BB - 1;
        int grow = ann[2 * b];
        *(uint4*)(femb_l + i * 1024 + ch * 16) =
            *(const uint4*)(femb + (long)grow * JJ + ch * 8);
    }
    // ---- per-row-slot metadata ----
    int bbrel[8]; float vv[8];
#pragma unroll
    for (int mt = 0; mt < 2; ++mt)
#pragma unroll
        for (int reg = 0; reg < 4; ++reg) {
            int m = m0 + wm * 32 + mt * 16 + lq * 4 + reg;
            bbrel[mt * 4 + reg] = m / SS - b_lo;
            vv[mt * 4 + reg] = valid[m];
        }
    __syncthreads();

    // ---- A fragments -> registers (80 VGPR) ----
    short8v areg[2][10];
#pragma unroll
    for (int mt = 0; mt < 2; ++mt) {
        int r = wm * 32 + mt * 16 + li;
#pragma unroll
        for (int kt = 0; kt < 10; ++kt) {
            int blk = (kt * 4 + lq) ^ (r & 7);
            areg[mt][kt] = *(const short8v*)(abuf + r * RB + (blk << 4));
        }
    }
    // prefetch B(jt=0, kh=0) into regs while areg reads drain
    uint4 st[5];
#pragma unroll
    for (int i = 0; i < 5; ++i) {
        int c = i * 256 + t; int r = c / 20, c20 = c - r * 20;
        st[i] = *(const uint4*)(Wsb + (long)r * KP + c20 * 8);
    }
    __syncthreads();   // areg reads done; A region reusable
#pragma unroll
    for (int i = 0; i < 5; ++i) {
        int c = i * 256 + t; int r = c / 20, c20 = c - r * 20;
        *(uint4*)(bbuf0 + r * BRB + ((c20 ^ (r & 7)) << 4)) = st[i];
    }
    float sp[8] = {0.f, 0.f, 0.f, 0.f, 0.f, 0.f, 0.f, 0.f};
    __syncthreads();   // bbuf0 visible

    const int rb0 = wn * 32 + li;       // B frag row (nt=0); nt=1 adds 16
    const int xs0 = rb0 & 7, xs1 = (rb0 + 16) & 7;

    for (int jt = 0; jt < 8; ++jt) {
        float4v acc[2][2] = {};

        // ======== half kh=0: compute from bbuf0, prefetch (jt,kh=1)->bbuf1 ====
#pragma unroll
        for (int i = 0; i < 5; ++i) {
            int c = i * 256 + t; int r = c / 20, c20 = c - r * 20;
            st[i] = *(const uint4*)(Wsb + (long)(jt * 64 + r) * KP + 160 + c20 * 8);
        }
#pragma unroll
        for (int kt = 0; kt < 5; ++kt) {
            short8v b0 = *(const short8v*)(bbuf0 + rb0 * BRB + (((kt * 4 + lq) ^ xs0) << 4));
            short8v b1 = *(const short8v*)(bbuf0 + (rb0 + 16) * BRB + (((kt * 4 + lq) ^ xs1) << 4));
            acc[0][0] = __builtin_amdgcn_mfma_f32_16x16x32_bf16(areg[0][kt], b0, acc[0][0], 0, 0, 0);
            acc[0][1] = __builtin_amdgcn_mfma_f32_16x16x32_bf16(areg[0][kt], b1, acc[0][1], 0, 0, 0);
            acc[1][0] = __builtin_amdgcn_mfma_f32_16x16x32_bf16(areg[1][kt], b0, acc[1][0], 0, 0, 0);
            acc[1][1] = __builtin_amdgcn_mfma_f32_16x16x32_bf16(areg[1][kt], b1, acc[1][1], 0, 0, 0);
        }
#pragma unroll
        for (int i = 0; i < 5; ++i) {
            int c = i * 256 + t; int r = c / 20, c20 = c - r * 20;
            *(uint4*)(bbuf1 + r * BRB + ((c20 ^ (r & 7)) << 4)) = st[i];
        }
        __syncthreads();

        // ======== half kh=1: compute from bbuf1, prefetch (jt+1,kh=0)->bbuf0 ==
        if (jt < 7) {
#pragma unroll
            for (int i = 0; i < 5; ++i) {
                int c = i * 256 + t; int r = c / 20, c20 = c - r * 20;
                st[i] = *(const uint4*)(Wsb + (long)((jt + 1) * 64 + r) * KP + c20 * 8);
            }
        }
#pragma unroll
        for (int kt = 0; kt < 5; ++kt) {
            short8v b0 = *(const short8v*)(bbuf1 + rb0 * BRB + (((kt * 4 + lq) ^ xs0) << 4));
            short8v b1 = *(const short8v*)(bbuf1 + (rb0 + 16) * BRB + (((kt * 4 + lq) ^ xs1) << 4));
            acc[0][0] = __builtin_amdgcn_mfma_f32_16x16x32_bf16(areg[0][5 + kt], b0, acc[0][0], 0, 0, 0);
            acc[0][1] = __builtin_amdgcn_mfma_f32_16x16x32_bf16(areg[0][5 + kt], b1, acc[0][1], 0, 0, 0);
            acc[1][0] = __builtin_amdgcn_mfma_f32_16x16x32_bf16(areg[1][5 + kt], b0, acc[1][0], 0, 0, 0);
            acc[1][1] = __builtin_amdgcn_mfma_f32_16x16x32_bf16(areg[1][5 + kt], b1, acc[1][1], 0, 0, 0);
        }

        // fused epilogue: tanh + w_fc partial reduction (femb from LDS)
#pragma unroll
        for (int nt = 0; nt < 2; ++nt) {
            int col = jt * 64 + wn * 32 + nt * 16 + li;
            float bs = b_sent[col], wf = w_fc[col], be = b_emb[col];
#pragma unroll
            for (int mt = 0; mt < 2; ++mt)
#pragma unroll
                for (int reg = 0; reg < 4; ++reg) {
                    int slot = mt * 4 + reg;
                    float fv = __bfloat162float(
                        *(const __hip_bfloat16*)(femb_l + bbrel[slot] * 1024 + col * 2));
                    float guid = (vv[slot] != 0.f) ? fv : be;
                    sp[slot] += tanh_fast(acc[mt][nt][reg] + bs + guid) * wf;
                }
        }

        if (jt < 7) {
#pragma unroll
            for (int i = 0; i < 5; ++i) {
                int c = i * 256 + t; int r = c / 20, c20 = c - r * 20;
                *(uint4*)(bbuf0 + r * BRB + ((c20 ^ (r & 7)) << 4)) = st[i];
            }
        }
        __syncthreads();
    }

    // reduce across the 16 li lanes per row-slot
#pragma unroll
    for (int slot = 0; slot < 8; ++slot) {
        float v = sp[slot];
        v += __shfl_xor(v, 1); v += __shfl_xor(v, 2);
        v += __shfl_xor(v, 4); v += __shfl_xor(v, 8);
        sp[slot] = v;
    }
    float* red = (float*)smem;
    if (li == 0) {
#pragma unroll
        for (int mt = 0; mt < 2; ++mt)
#pragma unroll
            for (int reg = 0; reg < 4; ++reg)
                red[wn * 64 + wm * 32 + mt * 16 + lq * 4 + reg] = sp[mt * 4 + reg];
    }
    __syncthreads();
    if (t < 64) scores[m0 + t] = red[t] + red[64 + t] + b_fc[0];
}

// ---------------- kernel 3: softmax + mask + renorm + weighted sum -------------
__global__ __launch_bounds__(256) void k3_out(const float* __restrict__ scores,
                                              const float* __restrict__ nonzero,
                                              const float* __restrict__ embedded,
                                              float* __restrict__ out) {
    __shared__ float wgt[3][SS];
    const int b0 = blockIdx.x * 3;
    const int t = threadIdx.x;
    if (t < 3) {
        int b = b0 + t;
        if (b < BB) {
            float sc[SS], nz[SS];
            float mx = -1e30f;
            for (int s = 0; s < SS; ++s) {
                sc[s] = scores[b * SS + s];
                nz[s] = nonzero[b * SS + s];
                mx = fmaxf(mx, sc[s]);
            }
            float den = 0.f, e[SS];
            for (int s = 0; s < SS; ++s) { e[s] = nz[s] * __expf(sc[s] - mx); den += e[s]; }
            float inv = 1.f / den;
            for (int s = 0; s < SS; ++s) wgt[t][s] = e[s] * inv;
        }
    }
    __syncthreads();
    if (t < 225) {
        int r = t / 75, q = t - r * 75;
        int b = b0 + r;
        if (b < BB) {
            float4 a; a.x = a.y = a.z = a.w = 0.f;
#pragma unroll
            for (int s = 0; s < SS; ++s) {
                float4 e = *(const float4*)(embedded + ((long)b * SS + s) * DD + q * 4);
                float ww = wgt[r][s];
                a.x += ww * e.x; a.y += ww * e.y; a.z += ww * e.z; a.w += ww * e.w;
            }
            *(float4*)(out + (long)b * DD + q * 4) = a;
        }
    }
}

extern "C" void kernel_launch(void* const* d_in, const int* in_sizes, int n_in,
                              void* d_out, int out_size, void* d_ws, size_t ws_size,
                              hipStream_t stream) {
    const float* context  = (const float*)d_in[0];
    const float* embedded = (const float*)d_in[1];
    const int*   labels   = (const int*)d_in[2];
    const float* guide    = (const float*)d_in[3];
    const int*   ann      = (const int*)d_in[4];
    const float* W_sent   = (const float*)d_in[5];
    const float* b_sent   = (const float*)d_in[6];
    const float* W_emb    = (const float*)d_in[7];
    const float* b_emb    = (const float*)d_in[8];
    const float* w_fc     = (const float*)d_in[9];
    const float* b_fc     = (const float*)d_in[10];
    float* out = (float*)d_out;

    char* w = (char*)d_ws;
    __hip_bfloat16* femb = (__hip_bfloat16*)(w);               // 1024*512*2 = 1048576
    float* valid         = (float*)(w + 1048576);
    float* nonzero       = (float*)(w + 1703936);
    float* scores        = (float*)(w + 2359296);
    __hip_bfloat16* Wsb  = (__hip_bfloat16*)(w + 3014656);
    __hip_bfloat16* Web  = (__hip_bfloat16*)(w + 3342336);
    __hip_bfloat16* Gb   = (__hip_bfloat16*)(w + 5505024);
    // total 9729024 bytes

    hipLaunchKernelGGL(kc_pad_bf16, dim3((JJ * KP + 255) / 256), dim3(256), 0, stream,
                       W_sent, Wsb, JJ, DD, KP);
    hipLaunchKernelGGL(kc_pad_bf16, dim3((JJ * 2112 + 255) / 256), dim3(256), 0, stream,
                       W_emb, Web, JJ, VGG, 2112);
    hipLaunchKernelGGL(kc_pad_bf16, dim3((NII * 2112 + 255) / 256), dim3(256), 0, stream,
                       guide, Gb, NII, VGG, 2112);
    hipLaunchKernelGGL(k0_valid, dim3(BB / 256), dim3(256), 0, stream,
                       labels, valid, nonzero);
    hipLaunchKernelGGL(k1_femb_mfma, dim3(16, JJ / 64), dim3(256), 0, stream,
                       Gb, Web, b_emb, femb);
    hipLaunchKernelGGL(k2_scores_mfma, dim3((BB * SS) / 64), dim3(256), 0, stream,
                       context, Wsb, b_sent, w_fc, b_fc, femb, ann, b_emb, valid, scores);
    hipLaunchKernelGGL(k3_out, dim3((BB + 2) / 3), dim3(256), 0, stream,
                       scores, nonzero, embedded, out);
}

// Round 6
// 250.013 us; speedup vs baseline: 2.0389x; 1.3965x over previous
//
#include <hip/hip_runtime.h>
#include <hip/hip_bf16.h>

#define BB 8192
#define SS 20
#define DD 300
#define JJ 512
#define NII 1000
#define VGG 2078
#define KP 328           // k2 K padded: 328 elems, 656B rows (41 16B-classes, ==1 mod 8)
#define RBY 656          // k2 LDS/global row bytes
#define BTILE 41984      // 64 * 656 bytes per jt B tile (contiguous in global)
#define BP1 72           // k1 64x64 chunk lds row stride

typedef __attribute__((ext_vector_type(8))) short short8v;
typedef __attribute__((ext_vector_type(4))) float float4v;

// tanh(x) = 1 - 2/(exp(2x)+1) ; saturates correctly at +/-inf
__device__ __forceinline__ float tanh_fast(float x) {
    float t = __expf(2.f * x);
    return 1.f - 2.f * __builtin_amdgcn_rcpf(t + 1.f);
}

__device__ __forceinline__ unsigned short bf16u(float x) {
    __hip_bfloat16 h = __float2bfloat16(x);
    return *(unsigned short*)&h;
}

// async global->LDS, 16B per lane; LDS dest = uniform base + lane*16
__device__ __forceinline__ void gload16(const void* g, void* l) {
    __builtin_amdgcn_global_load_lds(
        (const __attribute__((address_space(1))) unsigned int*)g,
        (__attribute__((address_space(3))) unsigned int*)l, 16, 0, 0);
}

// ---------------- pad+convert fp32 -> bf16 with zero pad on cols ----------------
__global__ __launch_bounds__(256) void kc_pad_bf16(const float* __restrict__ src,
                                                   __hip_bfloat16* __restrict__ dst,
                                                   int rows, int scols, int dcols) {
    int idx = blockIdx.x * 256 + threadIdx.x;
    if (idx >= rows * dcols) return;
    int r = idx / dcols, c = idx % dcols;
    float v = (c < scols) ? src[(long)r * scols + c] : 0.f;
    dst[idx] = __float2bfloat16(v);
}

// ---------------- kernel 0: valid / nonzero masks ----------------
__global__ __launch_bounds__(256) void k0_valid(const int* __restrict__ labels,
                                                float* __restrict__ valid,
                                                float* __restrict__ nonzero) {
    int b = blockIdx.x * blockDim.x + threadIdx.x;
    if (b >= BB) return;
    float v = 1.f;
    for (int s = 0; s < SS; ++s) {
        float nz = (labels[b * SS + s] != 0) ? 1.f : 0.f;
        v *= nz;
        nonzero[b * SS + s] = nz;
        valid[b * SS + s] = v;
    }
}

// ---------------- kernel 1 (MFMA): femb = bf16(guide @ W_emb^T + b_emb) --------
__global__ __launch_bounds__(256) void k1_femb_mfma(
    const __hip_bfloat16* __restrict__ Gb,   // [NII][2112]
    const __hip_bfloat16* __restrict__ Web,  // [JJ][2112]
    const float* __restrict__ b_emb,
    __hip_bfloat16* __restrict__ femb) {     // [1024][JJ]
    __shared__ __hip_bfloat16 Al[64 * BP1];
    __shared__ __hip_bfloat16 Bl[64 * BP1];
    const int t = threadIdx.x;
    const int m0 = blockIdx.x * 64;
    const int n0 = blockIdx.y * 64;
    const int lane = t & 63;
    const int w = t >> 6;
    const int wm = w >> 1, wn = w & 1;
    const int li = lane & 15, lq = lane >> 4;

    float4v acc[2][2] = {};

    for (int kt = 0; kt < 33; ++kt) {
        for (int c = t; c < 512; c += 256) {
            int rr = c >> 3, off = (c & 7) * 8;
            int gr = m0 + rr; if (gr > NII - 1) gr = NII - 1;
            *(uint4*)&Al[rr * BP1 + off] =
                *(const uint4*)(Gb + (long)gr * 2112 + kt * 64 + off);
            *(uint4*)&Bl[rr * BP1 + off] =
                *(const uint4*)(Web + (long)(n0 + rr) * 2112 + kt * 64 + off);
        }
        __syncthreads();
#pragma unroll
        for (int ks = 0; ks < 2; ++ks) {
            short8v a[2], b[2];
#pragma unroll
            for (int mt = 0; mt < 2; ++mt)
                a[mt] = *(const short8v*)&Al[(wm * 32 + mt * 16 + li) * BP1 + ks * 32 + lq * 8];
#pragma unroll
            for (int nt = 0; nt < 2; ++nt)
                b[nt] = *(const short8v*)&Bl[(wn * 32 + nt * 16 + li) * BP1 + ks * 32 + lq * 8];
#pragma unroll
            for (int mt = 0; mt < 2; ++mt)
#pragma unroll
                for (int nt = 0; nt < 2; ++nt)
                    acc[mt][nt] = __builtin_amdgcn_mfma_f32_16x16x32_bf16(
                        a[mt], b[nt], acc[mt][nt], 0, 0, 0);
        }
        __syncthreads();
    }
#pragma unroll
    for (int nt = 0; nt < 2; ++nt) {
        int col = n0 + wn * 32 + nt * 16 + li;
        float be = b_emb[col];
#pragma unroll
        for (int mt = 0; mt < 2; ++mt)
#pragma unroll
            for (int reg = 0; reg < 4; ++reg) {
                int row = wm * 32 + mt * 16 + lq * 4 + reg;
                femb[(long)(m0 + row) * JJ + col] = __float2bfloat16(acc[mt][nt][reg] + be);
            }
    }
}

// ---------------- kernel 2 (MFMA): fused scores -------------------------------
// BM=64 rows, 4 waves (2m x 2n), wave = 32r x 32c, K=300 pad 328.
// A staged once (cvt) into buf, pulled to areg[2][10]; then per jt the SAME buf
// receives the B tile via global_load_lds (contiguous 41984B memcpy from the
// pre-padded Wsb[512][328]). 656B rows => 16B-class stride 41 (==1 mod 8) =>
// b128 frag reads are 2-way-max bank aliased (free) with ZERO swizzle math.
// LDS 47.6KB -> 3 blocks/CU. No waves-per-EU hint: no reg cap, no spills.
__global__ __launch_bounds__(256) void k2_scores_mfma(
    const float* __restrict__ context,
    const __hip_bfloat16* __restrict__ Wsb,  // [JJ][KP] padded, zeros in k>=300
    const float* __restrict__ b_sent,
    const float* __restrict__ w_fc,
    const float* __restrict__ b_fc,
    const __hip_bfloat16* __restrict__ femb, // [1024][JJ]
    const int* __restrict__ ann,
    const float* __restrict__ b_emb,
    const float* __restrict__ valid,
    float* __restrict__ scores) {
    __shared__ __align__(16) char smem[48128];
    char* buf  = smem;                 // 41984: A-stage, then per-jt B tile
    char* fl   = smem + 41984;         // 5120: 5 femb rows [5][512] u16
    float* red = (float*)(smem + 47104); // 512: score reduction

    const int t = threadIdx.x;
    const int m0 = blockIdx.x * 64;
    const int b_lo = m0 / SS;
    const int lane = t & 63;
    const int w = t >> 6;
    const int wm = w >> 1, wn = w & 1;
    const int li = lane & 15, lq = lane >> 4;

    // ---- stage A: context f32 -> bf16 into buf[64][328], zero pad k>=300 ----
    for (int idx = t; idx < 64 * 82; idx += 256) {
        int r = idx / 82, q = idx - r * 82;
        ushort4 pk;
        if (q < 75) {
            float4 v = *(const float4*)(context + (long)(m0 + r) * DD + q * 4);
            pk.x = bf16u(v.x); pk.y = bf16u(v.y); pk.z = bf16u(v.z); pk.w = bf16u(v.w);
        } else { pk.x = pk.y = pk.z = pk.w = 0; }
        *(ushort4*)(buf + r * RBY + q * 8) = pk;
    }
    // ---- stage femb rows (<=5 distinct b) ----
    if (t < 320) {
        int i = t >> 6, ch = t & 63;
        int b = b_lo + i; if (b > BB - 1) b = BB - 1;
        int grow = ann[2 * b];
        *(uint4*)(fl + i * 1024 + ch * 16) =
            *(const uint4*)(femb + (long)grow * JJ + ch * 8);
    }
    // ---- per-row-slot metadata packed into bitmasks ----
    int brel0_0 = 0, brel0_1 = 0, selbits = 0, vbits = 0;
#pragma unroll
    for (int mt = 0; mt < 2; ++mt) {
        int base = m0 + wm * 32 + mt * 16 + lq * 4;
        int br0 = base / SS - b_lo;
        if (mt == 0) brel0_0 = br0; else brel0_1 = br0;
#pragma unroll
        for (int reg = 0; reg < 4; ++reg) {
            int m = base + reg;
            int slot = mt * 4 + reg;
            if (m / SS - b_lo != br0) selbits |= (1 << slot);
            if (valid[m] != 0.f)      vbits  |= (1 << slot);
        }
    }
    __syncthreads();

    // ---- A fragments -> registers (80 VGPR) ----
    short8v areg[2][10];
#pragma unroll
    for (int mt = 0; mt < 2; ++mt) {
        int r = wm * 32 + mt * 16 + li;
#pragma unroll
        for (int kt = 0; kt < 10; ++kt)
            areg[mt][kt] = *(const short8v*)(buf + r * RBY + kt * 64 + lq * 16);
    }
    __syncthreads();   // areg done; buf reusable for B tiles

    float sp[8] = {0.f, 0.f, 0.f, 0.f, 0.f, 0.f, 0.f, 0.f};
    const int rbB0 = (wn * 32 + li) * RBY;
    const int rbB1 = (wn * 32 + 16 + li) * RBY;

    for (int jt = 0; jt < 8; ++jt) {
        // ---- stage B tile jt: contiguous 41984B memcpy via global_load_lds ----
        const char* gB = (const char*)Wsb + (long)jt * BTILE;
        const int wbase = w * 656;     // 16B chunks owned by this wave
#pragma unroll
        for (int i = 0; i < 10; ++i)
            gload16(gB + (long)(wbase + i * 64 + lane) * 16,
                    buf + (wbase + i * 64) * 16);
        if (lane < 16)
            gload16(gB + (long)(wbase + 640 + lane) * 16,
                    buf + (wbase + 640) * 16);
        __syncthreads();   // drains vmcnt: B visible

        // ---- 40 MFMA over K=320 ----
        float4v acc[2][2] = {};
#pragma unroll
        for (int kt = 0; kt < 10; ++kt) {
            short8v b0 = *(const short8v*)(buf + rbB0 + kt * 64 + lq * 16);
            short8v b1 = *(const short8v*)(buf + rbB1 + kt * 64 + lq * 16);
            acc[0][0] = __builtin_amdgcn_mfma_f32_16x16x32_bf16(areg[0][kt], b0, acc[0][0], 0, 0, 0);
            acc[0][1] = __builtin_amdgcn_mfma_f32_16x16x32_bf16(areg[0][kt], b1, acc[0][1], 0, 0, 0);
            acc[1][0] = __builtin_amdgcn_mfma_f32_16x16x32_bf16(areg[1][kt], b0, acc[1][0], 0, 0, 0);
            acc[1][1] = __builtin_amdgcn_mfma_f32_16x16x32_bf16(areg[1][kt], b1, acc[1][1], 0, 0, 0);
        }

        // ---- fused epilogue: tanh + w_fc partial reduction ----
#pragma unroll
        for (int nt = 0; nt < 2; ++nt) {
            int col = jt * 64 + wn * 32 + nt * 16 + li;
            float bs = b_sent[col], wf = w_fc[col], be = b_emb[col];
#pragma unroll
            for (int mt = 0; mt < 2; ++mt) {
                int br = (mt == 0) ? brel0_0 : brel0_1;
                int br1 = (br < 4) ? br + 1 : 4;
                float f0 = __bfloat162float(*(const __hip_bfloat16*)(fl + br  * 1024 + col * 2));
                float f1 = __bfloat162float(*(const __hip_bfloat16*)(fl + br1 * 1024 + col * 2));
#pragma unroll
                for (int reg = 0; reg < 4; ++reg) {
                    int slot = mt * 4 + reg;
                    float fv = ((selbits >> slot) & 1) ? f1 : f0;
                    float g  = ((vbits  >> slot) & 1) ? fv : be;
                    sp[slot] += tanh_fast(acc[mt][nt][reg] + bs + g) * wf;
                }
            }
        }
        __syncthreads();   // compute done before next tile overwrites buf
    }

    // reduce across the 16 li lanes per row-slot
#pragma unroll
    for (int slot = 0; slot < 8; ++slot) {
        float v = sp[slot];
        v += __shfl_xor(v, 1); v += __shfl_xor(v, 2);
        v += __shfl_xor(v, 4); v += __shfl_xor(v, 8);
        sp[slot] = v;
    }
    if (li == 0) {
#pragma unroll
        for (int mt = 0; mt < 2; ++mt)
#pragma unroll
            for (int reg = 0; reg < 4; ++reg)
                red[wn * 64 + wm * 32 + mt * 16 + lq * 4 + reg] = sp[mt * 4 + reg];
    }
    __syncthreads();
    if (t < 64) scores[m0 + t] = red[t] + red[64 + t] + b_fc[0];
}

// ---------------- kernel 3: softmax + mask + renorm + weighted sum -------------
__global__ __launch_bounds__(256) void k3_out(const float* __restrict__ scores,
                                              const float* __restrict__ nonzero,
                                              const float* __restrict__ embedded,
                                              float* __restrict__ out) {
    __shared__ float wgt[3][SS];
    const int b0 = blockIdx.x * 3;
    const int t = threadIdx.x;
    if (t < 3) {
        int b = b0 + t;
        if (b < BB) {
            float sc[SS], nz[SS];
            float mx = -1e30f;
            for (int s = 0; s < SS; ++s) {
                sc[s] = scores[b * SS + s];
                nz[s] = nonzero[b * SS + s];
                mx = fmaxf(mx, sc[s]);
            }
            float den = 0.f, e[SS];
            for (int s = 0; s < SS; ++s) { e[s] = nz[s] * __expf(sc[s] - mx); den += e[s]; }
            float inv = 1.f / den;
            for (int s = 0; s < SS; ++s) wgt[t][s] = e[s] * inv;
        }
    }
    __syncthreads();
    if (t < 225) {
        int r = t / 75, q = t - r * 75;
        int b = b0 + r;
        if (b < BB) {
            float4 a; a.x = a.y = a.z = a.w = 0.f;
#pragma unroll
            for (int s = 0; s < SS; ++s) {
                float4 e = *(const float4*)(embedded + ((long)b * SS + s) * DD + q * 4);
                float ww = wgt[r][s];
                a.x += ww * e.x; a.y += ww * e.y; a.z += ww * e.z; a.w += ww * e.w;
            }
            *(float4*)(out + (long)b * DD + q * 4) = a;
        }
    }
}

extern "C" void kernel_launch(void* const* d_in, const int* in_sizes, int n_in,
                              void* d_out, int out_size, void* d_ws, size_t ws_size,
                              hipStream_t stream) {
    const float* context  = (const float*)d_in[0];
    const float* embedded = (const float*)d_in[1];
    const int*   labels   = (const int*)d_in[2];
    const float* guide    = (const float*)d_in[3];
    const int*   ann      = (const int*)d_in[4];
    const float* W_sent   = (const float*)d_in[5];
    const float* b_sent   = (const float*)d_in[6];
    const float* W_emb    = (const float*)d_in[7];
    const float* b_emb    = (const float*)d_in[8];
    const float* w_fc     = (const float*)d_in[9];
    const float* b_fc     = (const float*)d_in[10];
    float* out = (float*)d_out;

    char* w = (char*)d_ws;
    __hip_bfloat16* femb = (__hip_bfloat16*)(w);               // 1024*512*2 = 1048576
    float* valid         = (float*)(w + 1048576);              // 655360
    float* nonzero       = (float*)(w + 1703936);              // 655360
    float* scores        = (float*)(w + 2359296);              // 655360
    __hip_bfloat16* Wsb  = (__hip_bfloat16*)(w + 3014656);     // 512*328*2 = 335872
    __hip_bfloat16* Web  = (__hip_bfloat16*)(w + 3350528);     // 512*2112*2= 2162688
    __hip_bfloat16* Gb   = (__hip_bfloat16*)(w + 5513216);     // 1000*2112*2=4224000
    // total 9737216 bytes

    hipLaunchKernelGGL(kc_pad_bf16, dim3((JJ * KP + 255) / 256), dim3(256), 0, stream,
                       W_sent, Wsb, JJ, DD, KP);
    hipLaunchKernelGGL(kc_pad_bf16, dim3((JJ * 2112 + 255) / 256), dim3(256), 0, stream,
                       W_emb, Web, JJ, VGG, 2112);
    hipLaunchKernelGGL(kc_pad_bf16, dim3((NII * 2112 + 255) / 256), dim3(256), 0, stream,
                       guide, Gb, NII, VGG, 2112);
    hipLaunchKernelGGL(k0_valid, dim3(BB / 256), dim3(256), 0, stream,
                       labels, valid, nonzero);
    hipLaunchKernelGGL(k1_femb_mfma, dim3(16, JJ / 64), dim3(256), 0, stream,
                       Gb, Web, b_emb, femb);
    hipLaunchKernelGGL(k2_scores_mfma, dim3((BB * SS) / 64), dim3(256), 0, stream,
                       context, Wsb, b_sent, w_fc, b_fc, femb, ann, b_emb, valid, scores);
    hipLaunchKernelGGL(k3_out, dim3((BB + 2) / 3), dim3(256), 0, stream,
                       scores, nonzero, embedded, out);
}